// Round 6
// baseline (1549.083 us; speedup 1.0000x reference)
//
#include <hip/hip_runtime.h>

#define DI __device__ __forceinline__

typedef __bf16 bf16x8 __attribute__((ext_vector_type(8)));
typedef float f32x4 __attribute__((ext_vector_type(4)));
typedef unsigned short u16x8 __attribute__((ext_vector_type(8)));
typedef unsigned short u16x4 __attribute__((ext_vector_type(4)));

DI float frcp(float x) { return __builtin_amdgcn_rcpf(x); }
DI float fsig(float x) { return frcp(1.0f + __expf(-x)); }
DI float ftanh(float x) { return 1.0f - 2.0f * frcp(1.0f + __expf(2.0f * x)); }

// ---------------- conv 7x7 masked, 1 -> 16 ch, pad 3; x out channel-last ----
__global__ __launch_bounds__(256) void k_conv(const float* __restrict__ X,
                                              const float* __restrict__ Wc,
                                              const float* __restrict__ Bc,
                                              float* __restrict__ xo) {
    int n = blockIdx.x * 256 + threadIdx.x;
    int xx = n & 63, yy = (n >> 6) & 63, b = n >> 12;
    float acc[16];
#pragma unroll
    for (int o = 0; o < 16; ++o) acc[o] = Bc[o];
    const float* Xb = X + (size_t)b * 4096;
#pragma unroll
    for (int ky = 0; ky < 4; ++ky) {
        int yi = yy + ky - 3;
        if (yi < 0) continue;
        int kxmax = (ky == 3) ? 3 : 7;
        for (int kx = 0; kx < kxmax; ++kx) {
            int xi = xx + kx - 3;
            if (xi < 0 || xi > 63) continue;
            float v = Xb[yi * 64 + xi];
#pragma unroll
            for (int o = 0; o < 16; ++o)
                acc[o] = fmaf(Wc[o * 49 + ky * 7 + kx], v, acc[o]);
        }
    }
    float4* xp = reinterpret_cast<float4*>(xo + (size_t)n * 16);
#pragma unroll
    for (int q = 0; q < 4; ++q) {
        float4 t; t.x = acc[q*4]; t.y = acc[q*4+1]; t.z = acc[q*4+2]; t.w = acc[q*4+3];
        xp[q] = t;
    }
}

// ---------------- prep: residual combine + i2s GEMV into f32 G --------------
// x: [b][r][w][16] f32. fwd/bwd: [b][r][w][16] f32 (bwd un-reversed).
// G (f32): [dir][b][r][c0g][w][16], element p = mb*4+reg holds gate
//   g = mb*16 + c0g*4 + reg at scan-coord w (reversed for dir=1).
__global__ __launch_bounds__(256) void k_prep(float* __restrict__ x,
                                              const float* __restrict__ fwd,
                                              const float* __restrict__ bwdr,
                                              const float* __restrict__ wi_all,
                                              int layer, int addflag,
                                              float* __restrict__ G) {
    __shared__ float wsh[2048];  // [dir][g][c]
    for (int i = threadIdx.x; i < 2048; i += 256)
        wsh[i] = wi_all[layer * 2048 + i];
    __syncthreads();

    int n = blockIdx.x * 256 + threadIdx.x;
    int w = n & 63, r = (n >> 6) & 63, b = n >> 12;
    size_t pix = (size_t)n;

    float v[16];
    const float4* xp = reinterpret_cast<const float4*>(x + pix * 16);
#pragma unroll
    for (int q = 0; q < 4; ++q) {
        float4 t = xp[q];
        v[q*4] = t.x; v[q*4+1] = t.y; v[q*4+2] = t.z; v[q*4+3] = t.w;
    }
    if (addflag) {
        const float4* fp = reinterpret_cast<const float4*>(fwd + pix * 16);
#pragma unroll
        for (int q = 0; q < 4; ++q) {
            float4 t = fp[q];
            v[q*4] += t.x; v[q*4+1] += t.y; v[q*4+2] += t.z; v[q*4+3] += t.w;
        }
        if (r > 0) {
            const float4* bp = reinterpret_cast<const float4*>(bwdr + (pix - 64) * 16);
#pragma unroll
            for (int q = 0; q < 4; ++q) {
                float4 t = bp[q];
                v[q*4] += t.x; v[q*4+1] += t.y; v[q*4+2] += t.z; v[q*4+3] += t.w;
            }
        }
        float4* xps = reinterpret_cast<float4*>(x + pix * 16);
#pragma unroll
        for (int q = 0; q < 4; ++q) {
            float4 t; t.x = v[q*4]; t.y = v[q*4+1]; t.z = v[q*4+2]; t.w = v[q*4+3];
            xps[q] = t;
        }
    }

#pragma unroll
    for (int dir = 0; dir < 2; ++dir) {
        const float* wp = wsh + dir * 1024;
        int wg = dir ? (63 - w) : w;
#pragma unroll
        for (int c0g = 0; c0g < 4; ++c0g) {
            float val[16];
#pragma unroll
            for (int mb = 0; mb < 4; ++mb) {
#pragma unroll
                for (int reg = 0; reg < 4; ++reg) {
                    int g = mb * 16 + c0g * 4 + reg;
                    const float4* wr = reinterpret_cast<const float4*>(wp + g * 16);
                    float s = 0.f;
#pragma unroll
                    for (int c4 = 0; c4 < 4; ++c4) {
                        float4 a = wr[c4];
                        s = fmaf(a.x, v[c4*4+0], s);
                        s = fmaf(a.y, v[c4*4+1], s);
                        s = fmaf(a.z, v[c4*4+2], s);
                        s = fmaf(a.w, v[c4*4+3], s);
                    }
                    val[mb * 4 + reg] = s;
                }
            }
            float4* dst = reinterpret_cast<float4*>(
                G + ((((size_t)(dir * 32 + b) * 64 + r) * 4 + c0g) * 64 + wg) * 16);
#pragma unroll
            for (int q = 0; q < 4; ++q) {
                float4 t; t.x = val[q*4]; t.y = val[q*4+1]; t.z = val[q*4+2]; t.w = val[q*4+3];
                dst[q] = t;
            }
        }
    }
}

// ---------------- diagonal LSTM scan via split-precision MFMA ---------------
// One block per b, TWO co-resident scans (dir 0 and 1) of 4 waves each:
// 512 threads, 32 blocks -> 2 waves/SIMD so one scan's stalls hide under the
// other's VALU issue. Within a scan: wave wv owns rows r = 16*wv + (lane&15);
// kb = lane>>4 = k-block AND channel group c0 = kb*4.
// h kept as bf16 hi+lo planes in LDS; W as bf16 hi+lo in registers.
// s = Whi*Hhi + Whi*Hlo + Wlo*Hhi  (~17 mantissa bits, fp32-equivalent here).
__global__ __launch_bounds__(512, 2) void k_scan(const float* __restrict__ G,
                                                 const float* __restrict__ w0_all,
                                                 const float* __restrict__ w1_all,
                                                 const float* __restrict__ bi_all,
                                                 int layer,
                                                 float* __restrict__ fwdbuf,
                                                 float* __restrict__ bwdbuf) {
    int b = blockIdx.x;
    int t = threadIdx.x;
    int dir = t >> 8;          // scans: threads 0-255 = dir0, 256-511 = dir1
    int t8 = t & 255;
    int wv = t8 >> 6;
    int l = t & 63;
    int kb = l >> 4;
    int m = l & 15;
    int r = wv * 16 + m;
    int wb_ = (layer * 2 + dir) * 1024;

    // A fragments: A[g][k], k<16 -> W1[g][k], k>=16 -> W0[g][k-16].
    // lane kb holds k = kb*8..kb*8+7 (contiguous-k layout).
    const float* Wsel = (kb < 2 ? w1_all : w0_all) + wb_;
    int koff = (kb & 1) * 8;
    bf16x8 ahi[4], alo[4];
#pragma unroll
    for (int mb = 0; mb < 4; ++mb) {
        const float* wr = Wsel + (mb * 16 + m) * 16 + koff;
#pragma unroll
        for (int j = 0; j < 8; ++j) {
            float wv_ = wr[j];
            __bf16 hi = (__bf16)wv_;
            ahi[mb][j] = hi;
            alo[mb][j] = (__bf16)(wv_ - (float)hi);
        }
    }
    f32x4 biasv[4];
#pragma unroll
    for (int mb = 0; mb < 4; ++mb)
#pragma unroll
        for (int j = 0; j < 4; ++j)
            biasv[mb][j] = bi_all[(layer * 2 + dir) * 64 + mb * 16 + kb * 4 + j];

    // h double buffer x {hi,lo} planes per scan, bf16 bits.
    // Row q holds image row q-1 (q=0 = zero guard). Stride 24 halfs (48B).
    __shared__ __align__(16) unsigned short hbuf[2][2][2][65 * 24];
    for (int i = t; i < 2 * 2 * 2 * 65 * 24; i += 512) (&hbuf[0][0][0][0])[i] = 0;

    const float* Glane = G + (((size_t)(dir * 32 + b) * 64 + r) * 4 + kb) * 1024;
    float* ob = dir ? bwdbuf : fwdbuf;
    const size_t obase = (size_t)b * 65536;

    float cst[4] = {0.f, 0.f, 0.f, 0.f};
    f32x4 gr[4];
#pragma unroll
    for (int q = 0; q < 4; ++q) gr[q] = (f32x4){0.f, 0.f, 0.f, 0.f};
    if (r == 0) {  // prefetch G for tt=0 (w=0 only valid at r=0)
        const f32x4* gp = reinterpret_cast<const f32x4*>(Glane);
#pragma unroll
        for (int q = 0; q < 4; ++q) gr[q] = gp[q];
    }
    __syncthreads();

    int p = 0;
#pragma unroll 1
    for (int tt = 0; tt < 127; ++tt) {
        // prefetch G for tt+1
        f32x4 nr[4];
#pragma unroll
        for (int q = 0; q < 4; ++q) nr[q] = (f32x4){0.f, 0.f, 0.f, 0.f};
        int wn = tt + 1 - r;
        if ((unsigned)wn < 64u) {
            const f32x4* gp = reinterpret_cast<const f32x4*>(Glane + (size_t)wn * 16);
#pragma unroll
            for (int q = 0; q < 4; ++q) nr[q] = gp[q];
        }

        // B fragments: kb0: h[r][ch0..7], kb1: h[r][ch8..15], kb2/3: h[r-1][..]
        int q = r + 1 - (kb >> 1);
        int boff = q * 24 + (kb & 1) * 8;
        u16x8 bh_raw = *reinterpret_cast<const u16x8*>(&hbuf[dir][p][0][boff]);
        u16x8 bl_raw = *reinterpret_cast<const u16x8*>(&hbuf[dir][p][1][boff]);
        bf16x8 bhi = __builtin_bit_cast(bf16x8, bh_raw);
        bf16x8 blo = __builtin_bit_cast(bf16x8, bl_raw);

        // acc init = bias + G, then split-precision MFMA accumulate
        f32x4 acc[4];
#pragma unroll
        for (int mb = 0; mb < 4; ++mb) acc[mb] = biasv[mb] + gr[mb];
#pragma unroll
        for (int mb = 0; mb < 4; ++mb)
            acc[mb] = __builtin_amdgcn_mfma_f32_16x16x32_bf16(ahi[mb], bhi, acc[mb], 0, 0, 0);
#pragma unroll
        for (int mb = 0; mb < 4; ++mb)
            acc[mb] = __builtin_amdgcn_mfma_f32_16x16x32_bf16(ahi[mb], blo, acc[mb], 0, 0, 0);
#pragma unroll
        for (int mb = 0; mb < 4; ++mb)
            acc[mb] = __builtin_amdgcn_mfma_f32_16x16x32_bf16(alo[mb], bhi, acc[mb], 0, 0, 0);

        // gates: lane holds (o,f,i,g) for channels ch = kb*4+j of row r
        int wcur = tt - r;
        bool vout = (unsigned)wcur < 64u;
        float hv[4];
        u16x4 hih, lol;
#pragma unroll
        for (int j = 0; j < 4; ++j) {
            float so = acc[0][j], sf = acc[1][j], si = acc[2][j], sg = acc[3][j];
            float cn = fsig(sf) * cst[j] + fsig(si) * ftanh(sg);
            cst[j] = cn;
            float hn = fsig(so) * ftanh(cn);
            hv[j] = hn;
            __bf16 hi = (__bf16)hn;
            hih[j] = __builtin_bit_cast(unsigned short, hi);
            lol[j] = __builtin_bit_cast(unsigned short, (__bf16)(hn - (float)hi));
        }
        int widx = (r + 1) * 24 + kb * 4;
        *reinterpret_cast<u16x4*>(&hbuf[dir][p ^ 1][0][widx]) = hih;
        *reinterpret_cast<u16x4*>(&hbuf[dir][p ^ 1][1][widx]) = lol;
        if (vout) {
            int wo = dir ? (63 - wcur) : wcur;
            float4 hq; hq.x = hv[0]; hq.y = hv[1]; hq.z = hv[2]; hq.w = hv[3];
            *reinterpret_cast<float4*>(ob + obase + ((size_t)((r << 6) + wo) << 4) + kb * 4) = hq;
        }
#pragma unroll
        for (int qq = 0; qq < 4; ++qq) gr[qq] = nr[qq];

        asm volatile("s_waitcnt lgkmcnt(0)" ::: "memory");
        __builtin_amdgcn_sched_barrier(0);
        __builtin_amdgcn_s_barrier();
        __builtin_amdgcn_sched_barrier(0);
        p ^= 1;
    }
}

// ---------------- head: residual combine + 3-layer MLP ----------------------
__global__ __launch_bounds__(256) void k_head(const float* __restrict__ x,
                                              const float* __restrict__ fwd,
                                              const float* __restrict__ bwdr,
                                              const float* __restrict__ W1,
                                              const float* __restrict__ B1,
                                              const float* __restrict__ W2,
                                              const float* __restrict__ B2,
                                              const float* __restrict__ W3,
                                              const float* __restrict__ B3,
                                              float* __restrict__ out) {
    int n = blockIdx.x * 256 + threadIdx.x;
    int r = (n >> 6) & 63;
    size_t pix = (size_t)n;
    float v[16];
    const float4* xp = reinterpret_cast<const float4*>(x + pix * 16);
#pragma unroll
    for (int q = 0; q < 4; ++q) {
        float4 t = xp[q];
        v[q*4] = t.x; v[q*4+1] = t.y; v[q*4+2] = t.z; v[q*4+3] = t.w;
    }
    const float4* fp = reinterpret_cast<const float4*>(fwd + pix * 16);
#pragma unroll
    for (int q = 0; q < 4; ++q) {
        float4 t = fp[q];
        v[q*4] += t.x; v[q*4+1] += t.y; v[q*4+2] += t.z; v[q*4+3] += t.w;
    }
    if (r > 0) {
        const float4* bp = reinterpret_cast<const float4*>(bwdr + (pix - 64) * 16);
#pragma unroll
        for (int q = 0; q < 4; ++q) {
            float4 t = bp[q];
            v[q*4] += t.x; v[q*4+1] += t.y; v[q*4+2] += t.z; v[q*4+3] += t.w;
        }
    }
    float h1[16];
#pragma unroll
    for (int o = 0; o < 16; ++o) {
        float a = B1[o];
#pragma unroll
        for (int c = 0; c < 16; ++c) a = fmaf(W1[o * 16 + c], v[c], a);
        h1[o] = fmaxf(a, 0.f);
    }
    float h2[16];
#pragma unroll
    for (int o = 0; o < 16; ++o) {
        float a = B2[o];
#pragma unroll
        for (int c = 0; c < 16; ++c) a = fmaf(W2[o * 16 + c], h1[c], a);
        h2[o] = fmaxf(a, 0.f);
    }
    float y = B3[0];
#pragma unroll
    for (int c = 0; c < 16; ++c) y = fmaf(W3[c], h2[c], y);
    out[pix] = y;
}

extern "C" void kernel_launch(void* const* d_in, const int* in_sizes, int n_in,
                              void* d_out, int out_size, void* d_ws, size_t ws_size,
                              hipStream_t stream) {
    const float* X  = (const float*)d_in[0];
    const float* cw = (const float*)d_in[1];
    const float* cb = (const float*)d_in[2];
    const float* wi = (const float*)d_in[3];
    const float* bi = (const float*)d_in[4];
    const float* w0 = (const float*)d_in[5];
    const float* w1 = (const float*)d_in[6];
    const float* W1 = (const float*)d_in[7];
    const float* B1 = (const float*)d_in[8];
    const float* W2 = (const float*)d_in[9];
    const float* B2 = (const float*)d_in[10];
    const float* W3 = (const float*)d_in[11];
    const float* B3 = (const float*)d_in[12];
    float* out = (float*)d_out;

    char* ws = (char*)d_ws;
    float* x   = (float*)ws;                          //  8 MiB f32 [b][r][w][16]
    float* fwd = (float*)(ws + ((size_t)8 << 20));    //  8 MiB f32
    float* bwd = (float*)(ws + ((size_t)16 << 20));   //  8 MiB f32
    float* G   = (float*)(ws + ((size_t)24 << 20));   // 64 MiB f32

    k_conv<<<512, 256, 0, stream>>>(X, cw, cb, x);
    for (int l = 0; l < 7; ++l) {
        k_prep<<<512, 256, 0, stream>>>(x, fwd, bwd, wi, l, l > 0 ? 1 : 0, G);
        k_scan<<<32, 512, 0, stream>>>(G, w0, w1, bi, l, fwd, bwd);
    }
    k_head<<<512, 256, 0, stream>>>(x, fwd, bwd, W1, B1, W2, B2, W3, B3, out);
}

// Round 7
// 1004.290 us; speedup vs baseline: 1.5425x; 1.5425x over previous
//
#include <hip/hip_runtime.h>

#define DI __device__ __forceinline__

typedef __bf16 bf16x8 __attribute__((ext_vector_type(8)));
typedef float f32x4 __attribute__((ext_vector_type(4)));
typedef unsigned short u16x8 __attribute__((ext_vector_type(8)));
typedef unsigned short u16x4 __attribute__((ext_vector_type(4)));

DI float frcp(float x) { return __builtin_amdgcn_rcpf(x); }
DI float fsig(float x) { return frcp(1.0f + __expf(-x)); }
DI float ftanh(float x) { return 1.0f - 2.0f * frcp(1.0f + __expf(2.0f * x)); }

// ---------------- conv 7x7 masked, 1 -> 16 ch, pad 3; out channel-last ------
__global__ __launch_bounds__(256) void k_conv(const float* __restrict__ X,
                                              const float* __restrict__ Wc,
                                              const float* __restrict__ Bc,
                                              float* __restrict__ xo) {
    int n = blockIdx.x * 256 + threadIdx.x;
    int xx = n & 63, yy = (n >> 6) & 63, b = n >> 12;
    float acc[16];
#pragma unroll
    for (int o = 0; o < 16; ++o) acc[o] = Bc[o];
    const float* Xb = X + (size_t)b * 4096;
#pragma unroll
    for (int ky = 0; ky < 4; ++ky) {
        int yi = yy + ky - 3;
        if (yi < 0) continue;
        int kxmax = (ky == 3) ? 3 : 7;
        for (int kx = 0; kx < kxmax; ++kx) {
            int xi = xx + kx - 3;
            if (xi < 0 || xi > 63) continue;
            float v = Xb[yi * 64 + xi];
#pragma unroll
            for (int o = 0; o < 16; ++o)
                acc[o] = fmaf(Wc[o * 49 + ky * 7 + kx], v, acc[o]);
        }
    }
    float4* xp = reinterpret_cast<float4*>(xo + (size_t)n * 16);
#pragma unroll
    for (int q = 0; q < 4; ++q) {
        float4 t; t.x = acc[q*4]; t.y = acc[q*4+1]; t.z = acc[q*4+2]; t.w = acc[q*4+3];
        xp[q] = t;
    }
}

// ---------------- fused diagonal LSTM scan (i2s GEMV inlined) ---------------
// One block per (b,dir), 256 thr = 4 waves. Wave wv owns rows r=16wv+(lane&15);
// kb = lane>>4 = K-block for frags AND channel group c0=kb*4 for C/D.
// Per step: load v-inputs (V_{l-1}, fwd_{l-1}, bwd_{l-1}[r-1]) at the diagonal,
// v = sum (residual), then s = bias + Wi*v (2 MFMAs, K-packed split precision)
//                              + [W1|W0]*[h;h_up] (3 MFMAs, split precision).
// dir0/kb<2 lanes write the running residual V_l for the next layer.
// h kept as bf16 hi+lo planes in LDS (fp32-equivalent recurrence).
__global__ __launch_bounds__(256, 1) void k_scan(const float* __restrict__ Vin,
                                                 float* __restrict__ Vout,
                                                 const float* __restrict__ fwdIn,
                                                 const float* __restrict__ bwdIn,
                                                 float* __restrict__ fwdOut,
                                                 float* __restrict__ bwdOut,
                                                 const float* __restrict__ wi_all,
                                                 const float* __restrict__ w0_all,
                                                 const float* __restrict__ w1_all,
                                                 const float* __restrict__ bi_all,
                                                 int layer, int first) {
    int dir = blockIdx.x >> 5, b = blockIdx.x & 31;
    int t = threadIdx.x;
    int wv = t >> 6;
    int l = t & 63;
    int kb = l >> 4;
    int m = l & 15;
    int r = wv * 16 + m;
    int wb_ = (layer * 2 + dir) * 1024;

    // ---- main recurrent A frags: k<16 -> W1, k>=16 -> W0; lane kb holds
    //      k = kb*8..kb*8+7. Split bf16 hi/lo.
    const float* Wsel = (kb < 2 ? w1_all : w0_all) + wb_;
    int koff = (kb & 1) * 8;
    bf16x8 ahi[4], alo[4];
#pragma unroll
    for (int mb = 0; mb < 4; ++mb) {
        const float* wr = Wsel + (mb * 16 + m) * 16 + koff;
#pragma unroll
        for (int j = 0; j < 8; ++j) {
            float wv_ = wr[j];
            __bf16 hi = (__bf16)wv_;
            ahi[mb][j] = hi;
            alo[mb][j] = (__bf16)(wv_ - (float)hi);
        }
    }

    // ---- Wi A frags for the fused i2s GEMV.
    // xMFMA1: A = Wihi at ch cbase..cbase+7 on ALL kb (kb0/1 pair with vhi,
    //         kb2/3 pair with vlo). xMFMA2: A = Wilo on kb<2, zero on kb>=2.
    const float* Wi = wi_all + wb_;
    int cbase = (kb & 1) * 8;
    bf16x8 wihi[4], wiloz[4];
#pragma unroll
    for (int mb = 0; mb < 4; ++mb) {
        const float* wr = Wi + (mb * 16 + m) * 16 + cbase;
#pragma unroll
        for (int j = 0; j < 8; ++j) {
            float wv_ = wr[j];
            __bf16 hi = (__bf16)wv_;
            wihi[mb][j] = hi;
            wiloz[mb][j] = (kb < 2) ? (__bf16)(wv_ - (float)hi) : (__bf16)0.f;
        }
    }

    f32x4 biasv[4];
#pragma unroll
    for (int mb = 0; mb < 4; ++mb)
#pragma unroll
        for (int j = 0; j < 4; ++j)
            biasv[mb][j] = bi_all[(layer * 2 + dir) * 64 + mb * 16 + kb * 4 + j];

    // h double buffer x {hi,lo} planes, bf16 bits.
    // Row q holds image row q-1 (q=0 = zero guard). Stride 24 halfs (48B).
    __shared__ __align__(16) unsigned short hbuf[2][2][65 * 24];
    for (int i = t; i < 2 * 2 * 65 * 24; i += 256) (&hbuf[0][0][0])[i] = 0;

    const size_t rowbase  = ((size_t)b * 64 + r) * 64;        // pixel index of (r, 0)
    const size_t rowbaseU = ((size_t)b * 64 + (r - 1)) * 64;  // row above (r>=1)
    float* ob = dir ? bwdOut : fwdOut;
    bool vstore_lane = (!first) && (dir == 0) && (kb < 2);
    bool fb_load = !first;
    bool b_load = fb_load && (r > 0);

    float cst[4] = {0.f, 0.f, 0.f, 0.f};

    // current-step input regs (v components, 8 ch at cbase)
    f32x4 xc[2], fc[2], bc[2];
    {
        int w = 0 - r;
        bool valid = (unsigned)w < 64u;
#pragma unroll
        for (int q = 0; q < 2; ++q) { xc[q] = (f32x4){0,0,0,0}; fc[q] = (f32x4){0,0,0,0}; bc[q] = (f32x4){0,0,0,0}; }
        if (valid) {
            int wimg = dir ? (63 - w) : w;
            const f32x4* px = reinterpret_cast<const f32x4*>(Vin + (rowbase + wimg) * 16 + cbase);
            xc[0] = px[0]; xc[1] = px[1];
            if (fb_load) {
                const f32x4* pf = reinterpret_cast<const f32x4*>(fwdIn + (rowbase + wimg) * 16 + cbase);
                fc[0] = pf[0]; fc[1] = pf[1];
                if (b_load) {
                    const f32x4* pb = reinterpret_cast<const f32x4*>(bwdIn + (rowbaseU + wimg) * 16 + cbase);
                    bc[0] = pb[0]; bc[1] = pb[1];
                }
            }
        }
    }
    __syncthreads();

    int p = 0;
#pragma unroll 1
    for (int tt = 0; tt < 127; ++tt) {
        // ---- prefetch inputs for step tt+1 ----
        f32x4 xn[2], fn[2], bn[2];
#pragma unroll
        for (int q = 0; q < 2; ++q) { xn[q] = (f32x4){0,0,0,0}; fn[q] = (f32x4){0,0,0,0}; bn[q] = (f32x4){0,0,0,0}; }
        {
            int w = tt + 1 - r;
            if ((unsigned)w < 64u) {
                int wimg = dir ? (63 - w) : w;
                const f32x4* px = reinterpret_cast<const f32x4*>(Vin + (rowbase + wimg) * 16 + cbase);
                xn[0] = px[0]; xn[1] = px[1];
                if (fb_load) {
                    const f32x4* pf = reinterpret_cast<const f32x4*>(fwdIn + (rowbase + wimg) * 16 + cbase);
                    fn[0] = pf[0]; fn[1] = pf[1];
                    if (b_load) {
                        const f32x4* pb = reinterpret_cast<const f32x4*>(bwdIn + (rowbaseU + wimg) * 16 + cbase);
                        bn[0] = pb[0]; bn[1] = pb[1];
                    }
                }
            }
        }

        int wcur = tt - r;
        bool vout = (unsigned)wcur < 64u;
        int wo = dir ? (63 - wcur) : wcur;   // image coord of current step

        // ---- v = V_{l-1} + fwd + bwd_up (residual), split to bf16 hi/lo ----
        f32x4 v8[2];
#pragma unroll
        for (int q = 0; q < 2; ++q) v8[q] = xc[q] + fc[q] + bc[q];
        bf16x8 vsel;  // kb<2: vhi; kb>=2: vlo
#pragma unroll
        for (int q = 0; q < 2; ++q)
#pragma unroll
            for (int j = 0; j < 4; ++j) {
                float f = v8[q][j];
                __bf16 hi = (__bf16)f;
                vsel[q * 4 + j] = (kb < 2) ? hi : (__bf16)(f - (float)hi);
            }
        // write running residual V_l for next layer (dir0, kb<2 covers 16 ch)
        if (vstore_lane && vout) {
            f32x4* pv = reinterpret_cast<f32x4*>(Vout + (rowbase + wo) * 16 + cbase);
            pv[0] = v8[0]; pv[1] = v8[1];
        }

        // ---- acc = bias + Wi*v (2 MFMAs, independent of LDS) ----
        f32x4 acc[4];
#pragma unroll
        for (int mb = 0; mb < 4; ++mb) acc[mb] = biasv[mb];
#pragma unroll
        for (int mb = 0; mb < 4; ++mb)
            acc[mb] = __builtin_amdgcn_mfma_f32_16x16x32_bf16(wihi[mb], vsel, acc[mb], 0, 0, 0);
#pragma unroll
        for (int mb = 0; mb < 4; ++mb)
            acc[mb] = __builtin_amdgcn_mfma_f32_16x16x32_bf16(wiloz[mb], vsel, acc[mb], 0, 0, 0);

        // ---- recurrent term: B frags from LDS ----
        int q = r + 1 - (kb >> 1);
        int boff = q * 24 + (kb & 1) * 8;
        u16x8 bh_raw = *reinterpret_cast<const u16x8*>(&hbuf[p][0][boff]);
        u16x8 bl_raw = *reinterpret_cast<const u16x8*>(&hbuf[p][1][boff]);
        bf16x8 bhi = __builtin_bit_cast(bf16x8, bh_raw);
        bf16x8 blo = __builtin_bit_cast(bf16x8, bl_raw);
#pragma unroll
        for (int mb = 0; mb < 4; ++mb)
            acc[mb] = __builtin_amdgcn_mfma_f32_16x16x32_bf16(ahi[mb], bhi, acc[mb], 0, 0, 0);
#pragma unroll
        for (int mb = 0; mb < 4; ++mb)
            acc[mb] = __builtin_amdgcn_mfma_f32_16x16x32_bf16(ahi[mb], blo, acc[mb], 0, 0, 0);
#pragma unroll
        for (int mb = 0; mb < 4; ++mb)
            acc[mb] = __builtin_amdgcn_mfma_f32_16x16x32_bf16(alo[mb], bhi, acc[mb], 0, 0, 0);

        // ---- gates: lane holds (o,f,i,g) for channels ch = kb*4+j of row r ----
        float hv[4];
        u16x4 hih, lol;
#pragma unroll
        for (int j = 0; j < 4; ++j) {
            float so = acc[0][j], sf = acc[1][j], si = acc[2][j], sg = acc[3][j];
            float cn = fsig(sf) * cst[j] + fsig(si) * ftanh(sg);
            cst[j] = cn;
            float hn = fsig(so) * ftanh(cn);
            hv[j] = hn;
            __bf16 hi = (__bf16)hn;
            hih[j] = __builtin_bit_cast(unsigned short, hi);
            lol[j] = __builtin_bit_cast(unsigned short, (__bf16)(hn - (float)hi));
        }
        int widx = (r + 1) * 24 + kb * 4;
        *reinterpret_cast<u16x4*>(&hbuf[p ^ 1][0][widx]) = hih;
        *reinterpret_cast<u16x4*>(&hbuf[p ^ 1][1][widx]) = lol;
        if (vout) {
            float4 hq; hq.x = hv[0]; hq.y = hv[1]; hq.z = hv[2]; hq.w = hv[3];
            *reinterpret_cast<float4*>(ob + (rowbase + wo) * 16 + kb * 4) = hq;
        }
#pragma unroll
        for (int qq = 0; qq < 2; ++qq) { xc[qq] = xn[qq]; fc[qq] = fn[qq]; bc[qq] = bn[qq]; }

        asm volatile("s_waitcnt lgkmcnt(0)" ::: "memory");
        __builtin_amdgcn_sched_barrier(0);
        __builtin_amdgcn_s_barrier();
        __builtin_amdgcn_sched_barrier(0);
        p ^= 1;
    }
}

// ---------------- head: residual combine + 3-layer MLP ----------------------
__global__ __launch_bounds__(256) void k_head(const float* __restrict__ x,
                                              const float* __restrict__ fwd,
                                              const float* __restrict__ bwdr,
                                              const float* __restrict__ W1,
                                              const float* __restrict__ B1,
                                              const float* __restrict__ W2,
                                              const float* __restrict__ B2,
                                              const float* __restrict__ W3,
                                              const float* __restrict__ B3,
                                              float* __restrict__ out) {
    int n = blockIdx.x * 256 + threadIdx.x;
    int r = (n >> 6) & 63;
    size_t pix = (size_t)n;
    float v[16];
    const float4* xp = reinterpret_cast<const float4*>(x + pix * 16);
#pragma unroll
    for (int q = 0; q < 4; ++q) {
        float4 t = xp[q];
        v[q*4] = t.x; v[q*4+1] = t.y; v[q*4+2] = t.z; v[q*4+3] = t.w;
    }
    const float4* fp = reinterpret_cast<const float4*>(fwd + pix * 16);
#pragma unroll
    for (int q = 0; q < 4; ++q) {
        float4 t = fp[q];
        v[q*4] += t.x; v[q*4+1] += t.y; v[q*4+2] += t.z; v[q*4+3] += t.w;
    }
    if (r > 0) {
        const float4* bp = reinterpret_cast<const float4*>(bwdr + (pix - 64) * 16);
#pragma unroll
        for (int q = 0; q < 4; ++q) {
            float4 t = bp[q];
            v[q*4] += t.x; v[q*4+1] += t.y; v[q*4+2] += t.z; v[q*4+3] += t.w;
        }
    }
    float h1[16];
#pragma unroll
    for (int o = 0; o < 16; ++o) {
        float a = B1[o];
#pragma unroll
        for (int c = 0; c < 16; ++c) a = fmaf(W1[o * 16 + c], v[c], a);
        h1[o] = fmaxf(a, 0.f);
    }
    float h2[16];
#pragma unroll
    for (int o = 0; o < 16; ++o) {
        float a = B2[o];
#pragma unroll
        for (int c = 0; c < 16; ++c) a = fmaf(W2[o * 16 + c], h1[c], a);
        h2[o] = fmaxf(a, 0.f);
    }
    float y = B3[0];
#pragma unroll
    for (int c = 0; c < 16; ++c) y = fmaf(W3[c], h2[c], y);
    out[pix] = y;
}

extern "C" void kernel_launch(void* const* d_in, const int* in_sizes, int n_in,
                              void* d_out, int out_size, void* d_ws, size_t ws_size,
                              hipStream_t stream) {
    const float* X  = (const float*)d_in[0];
    const float* cw = (const float*)d_in[1];
    const float* cb = (const float*)d_in[2];
    const float* wi = (const float*)d_in[3];
    const float* bi = (const float*)d_in[4];
    const float* w0 = (const float*)d_in[5];
    const float* w1 = (const float*)d_in[6];
    const float* W1 = (const float*)d_in[7];
    const float* B1 = (const float*)d_in[8];
    const float* W2 = (const float*)d_in[9];
    const float* B2 = (const float*)d_in[10];
    const float* W3 = (const float*)d_in[11];
    const float* B3 = (const float*)d_in[12];
    float* out = (float*)d_out;

    char* ws = (char*)d_ws;
    float* V0 = (float*)ws;                          // 8 MiB  [b][r][w][16] f32
    float* V1 = (float*)(ws + ((size_t)8 << 20));    // 8 MiB
    float* f0 = (float*)(ws + ((size_t)16 << 20));   // 8 MiB
    float* b0 = (float*)(ws + ((size_t)24 << 20));   // 8 MiB
    float* f1 = (float*)(ws + ((size_t)32 << 20));   // 8 MiB
    float* b1 = (float*)(ws + ((size_t)40 << 20));   // 8 MiB

    k_conv<<<512, 256, 0, stream>>>(X, cw, cb, V0);
    for (int l = 0; l < 7; ++l) {
        const float* Vin = (l == 0) ? V0 : (((l - 1) & 1) ? V1 : V0);
        float* Vout = (l == 0) ? V1 : ((l & 1) ? V1 : V0);
        const float* fIn = ((l + 1) & 1) ? f1 : f0;  // fb[(l-1)&1]; unused l=0
        const float* bIn = ((l + 1) & 1) ? b1 : b0;
        float* fOut = (l & 1) ? f1 : f0;
        float* bOut = (l & 1) ? b1 : b0;
        k_scan<<<64, 256, 0, stream>>>(Vin, Vout, fIn, bIn, fOut, bOut,
                                       wi, w0, w1, bi, l, l == 0 ? 1 : 0);
    }
    // after l=6: V_6 in V0, fwd/bwd in f0/b0
    k_head<<<512, 256, 0, stream>>>(V0, f0, b0, W1, B1, W2, B2, W3, B3, out);
}